// Round 10
// baseline (247.680 us; speedup 1.0000x reference)
//
#include <hip/hip_runtime.h>
#include <hip/hip_cooperative_groups.h>

namespace cg = cooperative_groups;

#define N 8192
#define D 256

typedef short short8 __attribute__((ext_vector_type(8)));
typedef float f32x4 __attribute__((ext_vector_type(4)));

__device__ __forceinline__ unsigned short f2bf(float f) {
    unsigned int u = __float_as_uint(f);
    u += 0x7fffu + ((u >> 16) & 1u);   // RNE
    return (unsigned short)(u >> 16);
}
__device__ __forceinline__ float bf2f(unsigned short h) {
    return __uint_as_float(((unsigned int)h) << 16);
}

// load one 16-col fragment group (8 x 1KB wave-coalesced dwordx4) into regs
__device__ __forceinline__ void ld_b(const short8* __restrict__ xb8, int grp,
                                     int lane, short8 (&bv)[8]) {
#pragma unroll
    for (int kk = 0; kk < 8; ++kk)
        bv[kk] = xb8[(size_t)grp * 512 + kk * 64 + lane];
}

// compute one 256x16 subtile column: 32 MFMA + screened exp2 epilogue.
// Identical math/layout to the verified R13/R17/R18 kernels.
__device__ __forceinline__ void ct_compute(const short8 (&av)[4][8],
                                           const short8 (&bv)[8],
                                           float bc, const float (&ar)[16],
                                           float armax, float c2,
                                           float (&Sr)[16], float (&Mr)[16]) {
    f32x4 acc[4];
#pragma unroll
    for (int tr = 0; tr < 4; ++tr)
#pragma unroll
        for (int r = 0; r < 4; ++r) acc[tr][r] = 0.0f;

#pragma unroll
    for (int kk = 0; kk < 8; ++kk)
#pragma unroll
        for (int tr = 0; tr < 4; ++tr)
            acc[tr] = __builtin_amdgcn_mfma_f32_16x16x32_bf16(
                av[tr][kk], bv[kk], acc[tr], 0, 0, 0);

    // screen: conservative upper bound on t2 over this lane's 16 elems
    float gmax = acc[0][0];
#pragma unroll
    for (int tr = 0; tr < 4; ++tr)
#pragma unroll
        for (int r = 0; r < 4; ++r) gmax = fmaxf(gmax, acc[tr][r]);
    const float bound = fmaf(gmax, c2, armax + bc);

    if (__any(bound >= -115.0f)) {
        // exact slow path (diagonal-touching subtiles, ~1%)
#pragma unroll
        for (int tr = 0; tr < 4; ++tr)
#pragma unroll
            for (int r = 0; r < 4; ++r) {
                float g = acc[tr][r];
                float t2 = fminf(fmaf(g, c2, ar[tr * 4 + r] + bc), 0.0f);
                float e = __builtin_amdgcn_exp2f(t2);
                Sr[tr * 4 + r] += e;
                Mr[tr * 4 + r] = fmaf(e, t2, Mr[tr * 4 + r]);
            }
    }
    // else: all values underflow fp32 -> contribute exactly 0
}

// ---- phase bodies (verbatim ports of the verified standalone kernels) ----

__device__ __forceinline__ void cvt_body(const float* __restrict__ x,
                                         unsigned short* __restrict__ xb2,
                                         float* __restrict__ sq,
                                         float* __restrict__ Sarr,
                                         float* __restrict__ Larr,
                                         int grp, int lane) {
    const int c = lane & 15, q8 = lane >> 4;
    const int row = grp * 16 + c;

    float ssum = 0.0f;
#pragma unroll
    for (int kk = 0; kk < 8; ++kk) {
        const float4* gp = (const float4*)(x + (size_t)row * D + kk * 32 + q8 * 8);
        float4 v0 = gp[0], v1 = gp[1];
        unsigned short h[8];
        h[0] = f2bf(v0.x); h[1] = f2bf(v0.y); h[2] = f2bf(v0.z); h[3] = f2bf(v0.w);
        h[4] = f2bf(v1.x); h[5] = f2bf(v1.y); h[6] = f2bf(v1.z); h[7] = f2bf(v1.w);
        short8 p;
#pragma unroll
        for (int i = 0; i < 8; ++i) {
            float f = bf2f(h[i]);
            ssum = fmaf(f, f, ssum);
            p[i] = (short)h[i];
        }
        ((short8*)xb2)[(grp * 8 + kk) * 64 + lane] = p;
    }
    ssum += __shfl_xor(ssum, 16, 64);
    ssum += __shfl_xor(ssum, 32, 64);
    if (q8 == 0) {
        sq[row] = ssum;
        Sarr[row] = 0.0f;
        Larr[row] = 0.0f;
    }
}

__device__ __forceinline__ void gram_body(const unsigned short* __restrict__ xb2,
                                          const float* __restrict__ sq,
                                          float s2, float c2,
                                          float* __restrict__ Sarr,
                                          float* __restrict__ Larr,
                                          int bx, int by, int tid) {
    const int wv = tid >> 6, lane = tid & 63;
    const int q8 = lane >> 4, c = lane & 15;
    const int rowbase = bx * 256;
    const int ybase = by * 512;

    // A fragments: wave wv owns rows rowbase + wv*64 .. +63 (coalesced)
    short8 av[4][8];
#pragma unroll
    for (int tr = 0; tr < 4; ++tr) {
        const int grp = (rowbase >> 4) + wv * 4 + tr;
#pragma unroll
        for (int kk = 0; kk < 8; ++kk)
            av[tr][kk] = ((const short8*)xb2)[(grp * 8 + kk) * 64 + lane];
    }
    float ar[16];   // sq[row] * s2 (negative)
#pragma unroll
    for (int tr = 0; tr < 4; ++tr)
#pragma unroll
        for (int r = 0; r < 4; ++r)
            ar[tr * 4 + r] = sq[rowbase + wv * 64 + tr * 16 + q8 * 4 + r] * s2;
    float armax = ar[0];
#pragma unroll
    for (int k = 1; k < 16; ++k) armax = fmaxf(armax, ar[k]);

    float Sr[16], Mr[16];
#pragma unroll
    for (int k = 0; k < 16; ++k) { Sr[k] = 0.f; Mr[k] = 0.f; }

    const short8* xb8 = (const short8*)xb2;
    const int gbase = ybase >> 4;

    // depth-1 pipeline: prologue loads ct=0 (R18 structure, best measured)
    short8 bvA[8], bvB[8];
    float bcA, bcB;
    ld_b(xb8, gbase, lane, bvA);
    bcA = sq[ybase + c] * s2;

    for (int ct = 0; ct < 32; ct += 2) {
        ld_b(xb8, gbase + ct + 1, lane, bvB);
        bcB = sq[ybase + (ct + 1) * 16 + c] * s2;

        ct_compute(av, bvA, bcA, ar, armax, c2, Sr, Mr);

        const int nx = (ct + 2 < 32) ? ct + 2 : 0;
        ld_b(xb8, gbase + nx, lane, bvA);
        bcA = sq[ybase + nx * 16 + c] * s2;

        ct_compute(av, bvB, bcB, ar, armax, c2, Sr, Mr);
    }

    // row-sum commit: reduce across the 16 col-lanes (lane bits 0..3)
#pragma unroll
    for (int m = 1; m <= 8; m <<= 1)
#pragma unroll
        for (int k = 0; k < 16; ++k) {
            Sr[k] += __shfl_xor(Sr[k], m, 64);
            Mr[k] += __shfl_xor(Mr[k], m, 64);
        }
    if (c == 0) {
        const float LN2 = 0.69314718f;   // Mr holds sum e*log2(k); rescale to ln
#pragma unroll
        for (int k = 0; k < 16; ++k) {
            int row = rowbase + wv * 64 + (k >> 2) * 16 + q8 * 4 + (k & 3);
            atomicAdd(&Sarr[row], Sr[k]);
            atomicAdd(&Larr[row], Mr[k] * LN2);
        }
    }
}

__device__ __forceinline__ void finish_body(const float* __restrict__ x,
                                            const float* __restrict__ Sarr,
                                            const float* __restrict__ Larr,
                                            const float* __restrict__ target,
                                            const float* __restrict__ temp,
                                            float* __restrict__ out, int gid) {
    const int row = gid >> 6;                        // 64 float4 per row
    float S = Sarr[row], L = Larr[row];
    float H = __logf(S) - L / S;
    float z = (H - target[0]) / temp[0];
    float cs = 1.0f / (1.0f + __expf(z));
    float4 v = ((const float4*)x)[gid];
    float4 o;
    o.x = v.x * cs; o.y = v.y * cs; o.z = v.z * cs; o.w = v.w * cs;
    ((float4*)out)[gid] = o;
    if ((gid & 63) == 0) out[(size_t)N * D + row] = cs;  // control_signal section
}

// R23: single cooperative kernel = cvt -> grid.sync -> gram(R18) ->
// grid.sync -> finish. Motivation: dur fits C + k_gram with C ~= 76 us
// (fill 44 + cvt 4 + finish 3 + ~25 us launch/gap overhead); fusing
// removes 2 inter-kernel gaps (~12-16 us) without touching the verified
// gram structure. Grid 512x256 = exactly 2 blocks/CU at <=128 VGPR, 0 LDS
// -> co-residency guaranteed; guide G16 blesses hipLaunchCooperativeKernel
// under this harness. Fallback: if the coop launch is rejected, run the
// three standalone kernels (R18 behavior).
__global__ __launch_bounds__(256, 2) void k_fused(const float* __restrict__ x,
                                                  unsigned short* __restrict__ xb2,
                                                  float* __restrict__ sq,
                                                  float* __restrict__ Sarr,
                                                  float* __restrict__ Larr,
                                                  const float* __restrict__ target,
                                                  const float* __restrict__ temp,
                                                  float* __restrict__ out) {
    const int bid = blockIdx.x;          // 0..511
    const int tid = threadIdx.x;
    const int wv = tid >> 6, lane = tid & 63;

    // phase 1: cvt — 512 groups over blocks 0..127 x 4 waves
    if (bid < 128) cvt_body(x, xb2, sq, Sarr, Larr, bid * 4 + wv, lane);

    cg::this_grid().sync();

    // phase 2: gram — R18 mapping: grid (32,16) flattened
    {
        const float T = temp[0];
        const float LOG2E = 1.44269504f;
        const float s2 = -LOG2E / (2.0f * T * T);
        const float c2 = -2.0f * s2;
        gram_body(xb2, sq, s2, c2, Sarr, Larr, bid & 31, bid >> 5, tid);
    }

    cg::this_grid().sync();

    // phase 3: finish — grid-stride over N*64 float4 (4 per thread)
    {
        const int stride = 512 * 256;
        for (int gid = bid * 256 + tid; gid < N * (D / 4); gid += stride)
            finish_body(x, Sarr, Larr, target, temp, out, gid);
    }
}

// ---- standalone fallbacks (verbatim R18 kernels) ----

__global__ __launch_bounds__(64) void k_cvt(const float* __restrict__ x,
                                            unsigned short* __restrict__ xb2,
                                            float* __restrict__ sq,
                                            float* __restrict__ Sarr,
                                            float* __restrict__ Larr) {
    cvt_body(x, xb2, sq, Sarr, Larr, blockIdx.x, threadIdx.x & 63);
}

__global__ __launch_bounds__(256, 2) void k_gram(const unsigned short* __restrict__ xb2,
                                                 const float* __restrict__ sq,
                                                 const float* __restrict__ temp,
                                                 float* __restrict__ Sarr,
                                                 float* __restrict__ Larr) {
    const float T = temp[0];
    const float LOG2E = 1.44269504f;
    const float s2 = -LOG2E / (2.0f * T * T);
    const float c2 = -2.0f * s2;
    gram_body(xb2, sq, s2, c2, Sarr, Larr, blockIdx.x, blockIdx.y, threadIdx.x);
}

__global__ __launch_bounds__(256) void k_finish(const float* __restrict__ x,
                                                const float* __restrict__ Sarr,
                                                const float* __restrict__ Larr,
                                                const float* __restrict__ target,
                                                const float* __restrict__ temp,
                                                float* __restrict__ out) {
    finish_body(x, Sarr, Larr, target, temp, out, blockIdx.x * 256 + threadIdx.x);
}

extern "C" void kernel_launch(void* const* d_in, const int* in_sizes, int n_in,
                              void* d_out, int out_size, void* d_ws, size_t ws_size,
                              hipStream_t stream) {
    const float* x = (const float*)d_in[0];       // features [4,2048,256]
    const float* target = (const float*)d_in[7];  // target_entropy [1]
    const float* temp = (const float*)d_in[8];    // temperature [1]
    float* out = (float*)d_out;

    float* wsf = (float*)d_ws;
    float* sq = wsf;
    float* Sarr = wsf + N;
    float* Larr = wsf + 2 * N;

    // fragment-major bf16 copy of X: in ws if it fits, else park in d_out's
    // first 4 MB (finish only writes d_out after gram has consumed xb2)
    const size_t need = 3 * (size_t)N * sizeof(float) + (size_t)N * D * sizeof(unsigned short);
    unsigned short* xb2 = (ws_size >= need) ? (unsigned short*)(wsf + 3 * N)
                                            : (unsigned short*)d_out;

    void* args[] = {(void*)&x, (void*)&xb2, (void*)&sq, (void*)&Sarr,
                    (void*)&Larr, (void*)&target, (void*)&temp, (void*)&out};
    hipError_t err = hipLaunchCooperativeKernel((const void*)k_fused,
                                                dim3(512), dim3(256),
                                                args, 0, stream);
    if (err != hipSuccess) {
        // fallback: three-kernel path (R18 behavior)
        k_cvt<<<N / 16, 64, 0, stream>>>(x, xb2, sq, Sarr, Larr);
        k_gram<<<dim3(32, 16), 256, 0, stream>>>(xb2, sq, temp, Sarr, Larr);
        k_finish<<<(N * (D / 4)) / 256, 256, 0, stream>>>(x, Sarr, Larr, target, temp, out);
    }
}

// Round 12
// 114.624 us; speedup vs baseline: 2.1608x; 2.1608x over previous
//
#include <hip/hip_runtime.h>

#define N 8192
#define D 256

typedef short short8 __attribute__((ext_vector_type(8)));
typedef float f32x4 __attribute__((ext_vector_type(4)));

__device__ __forceinline__ unsigned short f2bf(float f) {
    unsigned int u = __float_as_uint(f);
    u += 0x7fffu + ((u >> 16) & 1u);   // RNE
    return (unsigned short)(u >> 16);
}
__device__ __forceinline__ float bf2f(unsigned short h) {
    return __uint_as_float(((unsigned int)h) << 16);
}

// Kernel 0 (R15 version, unchanged): fp32 -> bf16 into FRAGMENT-MAJOR xb2:
// 16B chunk ((row>>4)*8 + kk)*64 + lane holds
// X[(row>>4)*16 + (lane&15)][kk*32 + (lane>>4)*8 .. +8) as bf16.
// One wave per 16-row group, grid 512 x 64 -> all 256 CUs active.
// Also row squared norms + zero S/L accumulators.
__global__ __launch_bounds__(64) void k_cvt(const float* __restrict__ x,
                                            unsigned short* __restrict__ xb2,
                                            float* __restrict__ sq,
                                            float* __restrict__ Sarr,
                                            float* __restrict__ Larr) {
    const int lane = threadIdx.x & 63;
    const int c = lane & 15, q8 = lane >> 4;
    const int grp = blockIdx.x;               // 16-row group
    const int row = grp * 16 + c;

    float ssum = 0.0f;
#pragma unroll
    for (int kk = 0; kk < 8; ++kk) {
        const float4* gp = (const float4*)(x + (size_t)row * D + kk * 32 + q8 * 8);
        float4 v0 = gp[0], v1 = gp[1];
        unsigned short h[8];
        h[0] = f2bf(v0.x); h[1] = f2bf(v0.y); h[2] = f2bf(v0.z); h[3] = f2bf(v0.w);
        h[4] = f2bf(v1.x); h[5] = f2bf(v1.y); h[6] = f2bf(v1.z); h[7] = f2bf(v1.w);
        short8 p;
#pragma unroll
        for (int i = 0; i < 8; ++i) {
            float f = bf2f(h[i]);
            ssum = fmaf(f, f, ssum);
            p[i] = (short)h[i];
        }
        ((short8*)xb2)[(grp * 8 + kk) * 64 + lane] = p;
    }
    ssum += __shfl_xor(ssum, 16, 64);
    ssum += __shfl_xor(ssum, 32, 64);
    if (q8 == 0) {
        sq[row] = ssum;
        Sarr[row] = 0.0f;
        Larr[row] = 0.0f;
    }
}

// load one 16-col fragment group (8 x 1KB wave-coalesced dwordx4) into regs
__device__ __forceinline__ void ld_b(const short8* __restrict__ xb8, int grp,
                                     int lane, short8 (&bv)[8]) {
#pragma unroll
    for (int kk = 0; kk < 8; ++kk)
        bv[kk] = xb8[(size_t)grp * 512 + kk * 64 + lane];
}

// compute one 256x16 subtile column: 32 MFMA + screened exp2 epilogue.
// Same math as verified R13..R18. Difference vs R18: the per-row ar[]
// cache is gone — the (rare, diagonal-only) slow path reloads sq[row]
// on demand. armax is precomputed once; screen bound unchanged.
__device__ __forceinline__ void ct_compute(const short8 (&av)[4][8],
                                           const short8 (&bv)[8],
                                           float bc, float armax, float s2,
                                           float c2, const float* __restrict__ sq,
                                           int rowq, // rowbase + wv*64 + q8*4
                                           float (&Sr)[16], float (&Mr)[16]) {
    f32x4 acc[4];
#pragma unroll
    for (int tr = 0; tr < 4; ++tr)
#pragma unroll
        for (int r = 0; r < 4; ++r) acc[tr][r] = 0.0f;

#pragma unroll
    for (int kk = 0; kk < 8; ++kk)
#pragma unroll
        for (int tr = 0; tr < 4; ++tr)
            acc[tr] = __builtin_amdgcn_mfma_f32_16x16x32_bf16(
                av[tr][kk], bv[kk], acc[tr], 0, 0, 0);

    // screen: conservative upper bound on t2 over this lane's 16 elems
    float gmax = acc[0][0];
#pragma unroll
    for (int tr = 0; tr < 4; ++tr)
#pragma unroll
        for (int r = 0; r < 4; ++r) gmax = fmaxf(gmax, acc[tr][r]);
    const float bound = fmaf(gmax, c2, armax + bc);

    if (__any(bound >= -115.0f)) {
        // exact slow path (diagonal-touching subtiles, ~3%): reload sq here
#pragma unroll
        for (int tr = 0; tr < 4; ++tr)
#pragma unroll
            for (int r = 0; r < 4; ++r) {
                float arv = sq[rowq + tr * 16 + r] * s2;
                float g = acc[tr][r];
                float t2 = fminf(fmaf(g, c2, arv + bc), 0.0f);
                float e = __builtin_amdgcn_exp2f(t2);
                Sr[tr * 4 + r] += e;
                Mr[tr * 4 + r] = fmaf(e, t2, Mr[tr * 4 + r]);
            }
    }
    // else: all values underflow fp32 -> contribute exactly 0
}

// Kernel 1 (R24 resubmit; prior round was an infra failure, not a verdict).
// R18 structure + TRUE A-RESIDENCY via bounds(256,1).
// Model (closes on all R17-R23 data): k_gram is L2-BW-bound at 56 B/cyc/CU
// moving ~128 KB/CU/ct-step = B (64 KB) + a full A-RELOAD (64 KB) every
// iteration, because the true live set (~260 regs; av alone = 128) never
// fit hipcc's 128-reg allocation under bounds(256,2) — the compiler
// rematerializes av from L2 in-loop. Fix: bounds(256,1) lifts the cap to
// the 512-class (2 waves/SIMD still resident at <=256 regs); ar[16] cache
// dropped (slow path reloads sq on demand) to bring the live set to ~252.
// Everything else is R18 verbatim: grid (32,16), depth-1 B prefetch,
// identical math and layouts. Expected: A-reload traffic gone ->
// k_gram ~31 -> 17-21 us.
__global__ __launch_bounds__(256, 1) void k_gram(const unsigned short* __restrict__ xb2,
                                                 const float* __restrict__ sq,
                                                 const float* __restrict__ temp,
                                                 float* __restrict__ Sarr,
                                                 float* __restrict__ Larr) {
    const int tid = threadIdx.x;
    const int wv = tid >> 6, lane = tid & 63;
    const int q8 = lane >> 4, c = lane & 15;
    const int rowbase = blockIdx.x * 256;
    const int ybase = blockIdx.y * 512;
    const float T = temp[0];
    const float LOG2E = 1.44269504f;
    const float s2 = -LOG2E / (2.0f * T * T);   // log2-scaled; t2 = c2*g + ar + bc
    const float c2 = -2.0f * s2;

    // A fragments: wave wv owns rows rowbase + wv*64 .. +63 (coalesced)
    short8 av[4][8];
#pragma unroll
    for (int tr = 0; tr < 4; ++tr) {
        const int grp = (rowbase >> 4) + wv * 4 + tr;
#pragma unroll
        for (int kk = 0; kk < 8; ++kk)
            av[tr][kk] = ((const short8*)xb2)[(grp * 8 + kk) * 64 + lane];
    }
    // armax = max over this lane's 16 rows of sq*s2 (s2<0 -> use min of sq)
    const int rowq = rowbase + wv * 64 + q8 * 4;
    float armax;
    {
        float sqmin = sq[rowq + 0 * 16 + 0];
#pragma unroll
        for (int tr = 0; tr < 4; ++tr)
#pragma unroll
            for (int r = 0; r < 4; ++r)
                if (tr + r) sqmin = fminf(sqmin, sq[rowq + tr * 16 + r]);
        armax = sqmin * s2;
    }

    float Sr[16], Mr[16];
#pragma unroll
    for (int k = 0; k < 16; ++k) { Sr[k] = 0.f; Mr[k] = 0.f; }

    const short8* xb8 = (const short8*)xb2;
    const int gbase = ybase >> 4;

    // depth-1 pipeline: prologue loads ct=0 (R18 structure, best measured)
    short8 bvA[8], bvB[8];
    float bcA, bcB;
    ld_b(xb8, gbase, lane, bvA);
    bcA = sq[ybase + c] * s2;

    for (int ct = 0; ct < 32; ct += 2) {
        ld_b(xb8, gbase + ct + 1, lane, bvB);
        bcB = sq[ybase + (ct + 1) * 16 + c] * s2;

        ct_compute(av, bvA, bcA, armax, s2, c2, sq, rowq, Sr, Mr);

        const int nx = (ct + 2 < 32) ? ct + 2 : 0;
        ld_b(xb8, gbase + nx, lane, bvA);
        bcA = sq[ybase + nx * 16 + c] * s2;

        ct_compute(av, bvB, bcB, armax, s2, c2, sq, rowq, Sr, Mr);
    }

    // row-sum commit: reduce across the 16 col-lanes (lane bits 0..3)
#pragma unroll
    for (int m = 1; m <= 8; m <<= 1)
#pragma unroll
        for (int k = 0; k < 16; ++k) {
            Sr[k] += __shfl_xor(Sr[k], m, 64);
            Mr[k] += __shfl_xor(Mr[k], m, 64);
        }
    if (c == 0) {
        const float LN2 = 0.69314718f;   // Mr holds sum e*log2(k); rescale to ln
#pragma unroll
        for (int k = 0; k < 16; ++k) {
            int row = rowbase + wv * 64 + (k >> 2) * 16 + q8 * 4 + (k & 3);
            atomicAdd(&Sarr[row], Sr[k]);
            atomicAdd(&Larr[row], Mr[k] * LN2);
        }
    }
}

// Kernel 2 (merged ctrl+scale, unchanged): per row H = log(S) - L/S,
// cs = sigmoid(-(H - target)/T); write scaled features + control signal.
__global__ __launch_bounds__(256) void k_finish(const float* __restrict__ x,
                                                const float* __restrict__ Sarr,
                                                const float* __restrict__ Larr,
                                                const float* __restrict__ target,
                                                const float* __restrict__ temp,
                                                float* __restrict__ out) {
    const int gid = blockIdx.x * 256 + threadIdx.x;  // float4 index
    const int row = gid >> 6;                        // 64 float4 per row
    float S = Sarr[row], L = Larr[row];
    float H = __logf(S) - L / S;
    float z = (H - target[0]) / temp[0];
    float cs = 1.0f / (1.0f + __expf(z));
    float4 v = ((const float4*)x)[gid];
    float4 o;
    o.x = v.x * cs; o.y = v.y * cs; o.z = v.z * cs; o.w = v.w * cs;
    ((float4*)out)[gid] = o;
    if ((gid & 63) == 0) out[(size_t)N * D + row] = cs;  // control_signal section
}

extern "C" void kernel_launch(void* const* d_in, const int* in_sizes, int n_in,
                              void* d_out, int out_size, void* d_ws, size_t ws_size,
                              hipStream_t stream) {
    const float* x = (const float*)d_in[0];       // features [4,2048,256]
    const float* target = (const float*)d_in[7];  // target_entropy [1]
    const float* temp = (const float*)d_in[8];    // temperature [1]
    float* out = (float*)d_out;

    float* wsf = (float*)d_ws;
    float* sq = wsf;
    float* Sarr = wsf + N;
    float* Larr = wsf + 2 * N;

    // fragment-major bf16 copy of X: in ws if it fits, else park in d_out's
    // first 4 MB (k_finish only writes d_out after k_gram has consumed xb2)
    const size_t need = 3 * (size_t)N * sizeof(float) + (size_t)N * D * sizeof(unsigned short);
    unsigned short* xb2 = (ws_size >= need) ? (unsigned short*)(wsf + 3 * N)
                                            : (unsigned short*)d_out;

    k_cvt<<<N / 16, 64, 0, stream>>>(x, xb2, sq, Sarr, Larr);
    k_gram<<<dim3(32, 16), 256, 0, stream>>>(xb2, sq, temp, Sarr, Larr);
    k_finish<<<(N * (D / 4)) / 256, 256, 0, stream>>>(x, Sarr, Larr, target, temp, out);
}

// Round 13
// 109.174 us; speedup vs baseline: 2.2687x; 1.0499x over previous
//
#include <hip/hip_runtime.h>

#define N 8192
#define D 256

typedef short short8 __attribute__((ext_vector_type(8)));
typedef float f32x4 __attribute__((ext_vector_type(4)));

__device__ __forceinline__ unsigned short f2bf(float f) {
    unsigned int u = __float_as_uint(f);
    u += 0x7fffu + ((u >> 16) & 1u);   // RNE
    return (unsigned short)(u >> 16);
}
__device__ __forceinline__ float bf2f(unsigned short h) {
    return __uint_as_float(((unsigned int)h) << 16);
}

// Kernel 0 (R15 version, unchanged): fp32 -> bf16 into FRAGMENT-MAJOR xb2:
// 16B chunk ((row>>4)*8 + kk)*64 + lane holds
// X[(row>>4)*16 + (lane&15)][kk*32 + (lane>>4)*8 .. +8) as bf16.
// One wave per 16-row group, grid 512 x 64 -> all 256 CUs active.
// Also row squared norms + zero S/L accumulators.
__global__ __launch_bounds__(64) void k_cvt(const float* __restrict__ x,
                                            unsigned short* __restrict__ xb2,
                                            float* __restrict__ sq,
                                            float* __restrict__ Sarr,
                                            float* __restrict__ Larr) {
    const int lane = threadIdx.x & 63;
    const int c = lane & 15, q8 = lane >> 4;
    const int grp = blockIdx.x;               // 16-row group
    const int row = grp * 16 + c;

    float ssum = 0.0f;
#pragma unroll
    for (int kk = 0; kk < 8; ++kk) {
        const float4* gp = (const float4*)(x + (size_t)row * D + kk * 32 + q8 * 8);
        float4 v0 = gp[0], v1 = gp[1];
        unsigned short h[8];
        h[0] = f2bf(v0.x); h[1] = f2bf(v0.y); h[2] = f2bf(v0.z); h[3] = f2bf(v0.w);
        h[4] = f2bf(v1.x); h[5] = f2bf(v1.y); h[6] = f2bf(v1.z); h[7] = f2bf(v1.w);
        short8 p;
#pragma unroll
        for (int i = 0; i < 8; ++i) {
            float f = bf2f(h[i]);
            ssum = fmaf(f, f, ssum);
            p[i] = (short)h[i];
        }
        ((short8*)xb2)[(grp * 8 + kk) * 64 + lane] = p;
    }
    ssum += __shfl_xor(ssum, 16, 64);
    ssum += __shfl_xor(ssum, 32, 64);
    if (q8 == 0) {
        sq[row] = ssum;
        Sarr[row] = 0.0f;
        Larr[row] = 0.0f;
    }
}

// load one 16-col fragment group (8 x 1KB wave-coalesced dwordx4) into regs
__device__ __forceinline__ void ld_b(const short8* __restrict__ xb8, int grp,
                                     int lane, short8 (&bv)[8]) {
#pragma unroll
    for (int kk = 0; kk < 8; ++kk)
        bv[kk] = xb8[(size_t)grp * 512 + kk * 64 + lane];
}

// compute one 256x16 subtile column: 32 MFMA + screened exp2 epilogue.
// Identical math/layout to the verified R13/R16/R17/R18 kernels.
__device__ __forceinline__ void ct_compute(const short8 (&av)[4][8],
                                           const short8 (&bv)[8],
                                           float bc, const float (&ar)[16],
                                           float armax, float c2,
                                           float (&Sr)[16], float (&Mr)[16]) {
    f32x4 acc[4];
#pragma unroll
    for (int tr = 0; tr < 4; ++tr)
#pragma unroll
        for (int r = 0; r < 4; ++r) acc[tr][r] = 0.0f;

#pragma unroll
    for (int kk = 0; kk < 8; ++kk)
#pragma unroll
        for (int tr = 0; tr < 4; ++tr)
            acc[tr] = __builtin_amdgcn_mfma_f32_16x16x32_bf16(
                av[tr][kk], bv[kk], acc[tr], 0, 0, 0);

    // screen: conservative upper bound on t2 over this lane's 16 elems
    float gmax = acc[0][0];
#pragma unroll
    for (int tr = 0; tr < 4; ++tr)
#pragma unroll
        for (int r = 0; r < 4; ++r) gmax = fmaxf(gmax, acc[tr][r]);
    const float bound = fmaf(gmax, c2, armax + bc);

    if (__any(bound >= -115.0f)) {
        // exact slow path (diagonal-touching subtiles, ~1%)
#pragma unroll
        for (int tr = 0; tr < 4; ++tr)
#pragma unroll
            for (int r = 0; r < 4; ++r) {
                float g = acc[tr][r];
                float t2 = fminf(fmaf(g, c2, ar[tr * 4 + r] + bc), 0.0f);
                float e = __builtin_amdgcn_exp2f(t2);
                Sr[tr * 4 + r] += e;
                Mr[tr * 4 + r] = fmaf(e, t2, Mr[tr * 4 + r]);
            }
    }
    // else: all values underflow fp32 -> contribute exactly 0
}

// Kernel 1 (R25 = R18 VERBATIM RESTORE — session-best 107.3 us).
// Final ledger on this kernel's structure (R17-R24, all counter-attributed):
// depth-1 reg prefetch -16us (R18); depth-2 prefetch -> 128-VGPR spill
// (R22, +85); TLP x2 via grid split: null (R20); symmetry work-halving:
// null (R21); coop-fused phases -> spill (R23); bounds(256,1) A-residency:
// null-negative (R24). Both pipes sit ~50% (MFMA demand ~16.6us, L2
// traffic ~14.6us, measured 31us ~= the SUM): the floor is per-iteration
// latency exposure under the hard 128-VGPR allocation wall — not a
// classical roofline, and deeper pipelining without register growth is
// below HIP source level (cf. the m97 ceiling). R18's exact config is
// the measured optimum; everything else regressed.
__global__ __launch_bounds__(256, 2) void k_gram(const unsigned short* __restrict__ xb2,
                                                 const float* __restrict__ sq,
                                                 const float* __restrict__ temp,
                                                 float* __restrict__ Sarr,
                                                 float* __restrict__ Larr) {
    const int tid = threadIdx.x;
    const int wv = tid >> 6, lane = tid & 63;
    const int q8 = lane >> 4, c = lane & 15;
    const int rowbase = blockIdx.x * 256;
    const int ybase = blockIdx.y * 512;
    const float T = temp[0];
    const float LOG2E = 1.44269504f;
    const float s2 = -LOG2E / (2.0f * T * T);   // log2-scaled; t2 = c2*g + ar + bc
    const float c2 = -2.0f * s2;

    // A fragments: wave wv owns rows rowbase + wv*64 .. +63 (coalesced)
    short8 av[4][8];
#pragma unroll
    for (int tr = 0; tr < 4; ++tr) {
        const int grp = (rowbase >> 4) + wv * 4 + tr;
#pragma unroll
        for (int kk = 0; kk < 8; ++kk)
            av[tr][kk] = ((const short8*)xb2)[(grp * 8 + kk) * 64 + lane];
    }
    float ar[16];   // sq[row] * s2 (negative)
#pragma unroll
    for (int tr = 0; tr < 4; ++tr)
#pragma unroll
        for (int r = 0; r < 4; ++r)
            ar[tr * 4 + r] = sq[rowbase + wv * 64 + tr * 16 + q8 * 4 + r] * s2;
    float armax = ar[0];
#pragma unroll
    for (int k = 1; k < 16; ++k) armax = fmaxf(armax, ar[k]);

    float Sr[16], Mr[16];
#pragma unroll
    for (int k = 0; k < 16; ++k) { Sr[k] = 0.f; Mr[k] = 0.f; }

    const short8* xb8 = (const short8*)xb2;
    const int gbase = ybase >> 4;

    // depth-1 pipeline: prologue loads ct=0
    short8 bvA[8], bvB[8];
    float bcA, bcB;
    ld_b(xb8, gbase, lane, bvA);
    bcA = sq[ybase + c] * s2;

    for (int ct = 0; ct < 32; ct += 2) {
        // prefetch ct+1 while computing ct
        ld_b(xb8, gbase + ct + 1, lane, bvB);
        bcB = sq[ybase + (ct + 1) * 16 + c] * s2;

        ct_compute(av, bvA, bcA, ar, armax, c2, Sr, Mr);

        // prefetch ct+2 while computing ct+1 (tail: harmless refetch of 0)
        const int nx = (ct + 2 < 32) ? ct + 2 : 0;
        ld_b(xb8, gbase + nx, lane, bvA);
        bcA = sq[ybase + nx * 16 + c] * s2;

        ct_compute(av, bvB, bcB, ar, armax, c2, Sr, Mr);
    }

    // row-sum commit: reduce across the 16 col-lanes (lane bits 0..3)
#pragma unroll
    for (int m = 1; m <= 8; m <<= 1)
#pragma unroll
        for (int k = 0; k < 16; ++k) {
            Sr[k] += __shfl_xor(Sr[k], m, 64);
            Mr[k] += __shfl_xor(Mr[k], m, 64);
        }
    if (c == 0) {
        const float LN2 = 0.69314718f;   // Mr holds sum e*log2(k); rescale to ln
#pragma unroll
        for (int k = 0; k < 16; ++k) {
            int row = rowbase + wv * 64 + (k >> 2) * 16 + q8 * 4 + (k & 3);
            atomicAdd(&Sarr[row], Sr[k]);
            atomicAdd(&Larr[row], Mr[k] * LN2);
        }
    }
}

// Kernel 2 (merged ctrl+scale, unchanged): per row H = log(S) - L/S,
// cs = sigmoid(-(H - target)/T); write scaled features + control signal.
__global__ __launch_bounds__(256) void k_finish(const float* __restrict__ x,
                                                const float* __restrict__ Sarr,
                                                const float* __restrict__ Larr,
                                                const float* __restrict__ target,
                                                const float* __restrict__ temp,
                                                float* __restrict__ out) {
    const int gid = blockIdx.x * 256 + threadIdx.x;  // float4 index
    const int row = gid >> 6;                        // 64 float4 per row
    float S = Sarr[row], L = Larr[row];
    float H = __logf(S) - L / S;
    float z = (H - target[0]) / temp[0];
    float cs = 1.0f / (1.0f + __expf(z));
    float4 v = ((const float4*)x)[gid];
    float4 o;
    o.x = v.x * cs; o.y = v.y * cs; o.z = v.z * cs; o.w = v.w * cs;
    ((float4*)out)[gid] = o;
    if ((gid & 63) == 0) out[(size_t)N * D + row] = cs;  // control_signal section
}

extern "C" void kernel_launch(void* const* d_in, const int* in_sizes, int n_in,
                              void* d_out, int out_size, void* d_ws, size_t ws_size,
                              hipStream_t stream) {
    const float* x = (const float*)d_in[0];       // features [4,2048,256]
    const float* target = (const float*)d_in[7];  // target_entropy [1]
    const float* temp = (const float*)d_in[8];    // temperature [1]
    float* out = (float*)d_out;

    float* wsf = (float*)d_ws;
    float* sq = wsf;
    float* Sarr = wsf + N;
    float* Larr = wsf + 2 * N;

    // fragment-major bf16 copy of X: in ws if it fits, else park in d_out's
    // first 4 MB (k_finish only writes d_out after k_gram has consumed xb2)
    const size_t need = 3 * (size_t)N * sizeof(float) + (size_t)N * D * sizeof(unsigned short);
    unsigned short* xb2 = (ws_size >= need) ? (unsigned short*)(wsf + 3 * N)
                                            : (unsigned short*)d_out;

    k_cvt<<<N / 16, 64, 0, stream>>>(x, xb2, sq, Sarr, Larr);
    k_gram<<<dim3(32, 16), 256, 0, stream>>>(xb2, sq, temp, Sarr, Larr);
    k_finish<<<(N * (D / 4)) / 256, 256, 0, stream>>>(x, Sarr, Larr, target, temp, out);
}